// Round 1
// baseline (1417.970 us; speedup 1.0000x reference)
//
#include <hip/hip_runtime.h>

#define NN 100000
#define NE 1000000
#define FIN 64
#define FHID 32

// ---------------- degree (counts of dst) ----------------
__global__ __launch_bounds__(256) void k_deg(const int* __restrict__ dst, int* __restrict__ deg) {
    int i = blockIdx.x * 256 + threadIdx.x;
    int stride = gridDim.x * 256;
    for (; i < NE; i += stride) atomicAdd(&deg[dst[i]], 1);
}

// ---------------- dis = rsqrt(deg+1) ----------------
__global__ __launch_bounds__(256) void k_dis(const int* __restrict__ deg, float* __restrict__ dis) {
    int i = blockIdx.x * 256 + threadIdx.x;
    if (i < NN) dis[i] = rsqrtf((float)deg[i] + 1.0f);
}

// ---------------- h1 = x @ W1   [NN,64]x[64,32] ----------------
__global__ __launch_bounds__(256) void k_gemm1(const float* __restrict__ x, const float* __restrict__ W1,
                                               float* __restrict__ h1) {
    __shared__ float Wl[FIN * FHID];  // 2048 f32 = 8KB
    for (int t = threadIdx.x; t < FIN * FHID; t += 256) Wl[t] = W1[t];
    __syncthreads();
    int row = blockIdx.x * 8 + (threadIdx.x >> 5);
    int col = threadIdx.x & 31;
    if (row >= NN) return;
    const float* xr = x + (size_t)row * FIN;
    float acc = 0.f;
#pragma unroll
    for (int k = 0; k < FIN; ++k) acc += xr[k] * Wl[k * FHID + col];
    h1[(size_t)row * FHID + col] = acc;
}

// ---------------- edge scatter layer1: agg[dst] += h1[src]*norm ----------------
__global__ __launch_bounds__(256) void k_agg1(const int* __restrict__ ei, const float* __restrict__ dis,
                                              const float* __restrict__ h1, float* __restrict__ agg) {
    int t = blockIdx.x * 256 + threadIdx.x;
    int e = t >> 3;
    int l = t & 7;
    if (e >= NE) return;
    int s = ei[e];
    int d = ei[NE + e];
    float nrm = dis[s] * dis[d];
    const float4 v = *reinterpret_cast<const float4*>(h1 + (size_t)s * FHID + l * 4);
    float* o = agg + (size_t)d * FHID + l * 4;
    atomicAdd(o + 0, v.x * nrm);
    atomicAdd(o + 1, v.y * nrm);
    atomicAdd(o + 2, v.z * nrm);
    atomicAdd(o + 3, v.w * nrm);
}

// ---------------- epilogue1: h = relu(agg + h1*dis^2 + b1), in place into agg ----------------
__global__ __launch_bounds__(256) void k_epi1(float* __restrict__ agg, const float* __restrict__ h1,
                                              const float* __restrict__ dis, const float* __restrict__ b1) {
    int i = blockIdx.x * 256 + threadIdx.x;
    if (i >= NN * FHID) return;
    int n = i >> 5;
    int c = i & 31;
    float di = dis[n];
    float v = agg[i] + h1[i] * (di * di) + b1[c];
    agg[i] = v > 0.f ? v : 0.f;
}

// ---------------- h2 = h @ W2   [NN,32]x[32,64] ----------------
__global__ __launch_bounds__(256) void k_gemm2(const float* __restrict__ h, const float* __restrict__ W2,
                                               float* __restrict__ h2) {
    __shared__ float Wl[FHID * FIN];  // 2048 f32
    for (int t = threadIdx.x; t < FHID * FIN; t += 256) Wl[t] = W2[t];
    __syncthreads();
    int row = blockIdx.x * 4 + (threadIdx.x >> 6);
    int col = threadIdx.x & 63;
    if (row >= NN) return;
    const float* hr = h + (size_t)row * FHID;
    float acc = 0.f;
#pragma unroll
    for (int k = 0; k < FHID; ++k) acc += hr[k] * Wl[k * FIN + col];
    h2[(size_t)row * FIN + col] = acc;
}

// ---------------- edge scatter layer2: out[dst] += h2[src]*norm ----------------
__global__ __launch_bounds__(256) void k_agg2(const int* __restrict__ ei, const float* __restrict__ dis,
                                              const float* __restrict__ h2, float* __restrict__ out) {
    int t = blockIdx.x * 256 + threadIdx.x;
    int e = t >> 4;
    int l = t & 15;
    if (e >= NE) return;
    int s = ei[e];
    int d = ei[NE + e];
    float nrm = dis[s] * dis[d];
    const float4 v = *reinterpret_cast<const float4*>(h2 + (size_t)s * FIN + l * 4);
    float* o = out + (size_t)d * FIN + l * 4;
    atomicAdd(o + 0, v.x * nrm);
    atomicAdd(o + 1, v.y * nrm);
    atomicAdd(o + 2, v.z * nrm);
    atomicAdd(o + 3, v.w * nrm);
}

// ---------------- epilogue2: out += h2*dis^2 + b2 ----------------
__global__ __launch_bounds__(256) void k_epi2(const float* __restrict__ h2, const float* __restrict__ dis,
                                              const float* __restrict__ b2, float* __restrict__ out) {
    int i = blockIdx.x * 256 + threadIdx.x;
    if (i >= NN * FIN) return;
    int n = i >> 6;
    int c = i & 63;
    float di = dis[n];
    out[i] += h2[i] * (di * di) + b2[c];
}

extern "C" void kernel_launch(void* const* d_in, const int* in_sizes, int n_in,
                              void* d_out, int out_size, void* d_ws, size_t ws_size,
                              hipStream_t stream) {
    const float* x  = (const float*)d_in[0];
    const int*   ei = (const int*)d_in[1];
    const float* W1 = (const float*)d_in[2];
    const float* b1 = (const float*)d_in[3];
    const float* W2 = (const float*)d_in[4];
    const float* b2 = (const float*)d_in[5];
    float* out = (float*)d_out;

    char* w = (char*)d_ws;
    auto align = [](size_t v) { return (v + 255) & ~(size_t)255; };
    int*   deg  = (int*)w;   w += align((size_t)NN * 4);
    float* dis  = (float*)w; w += align((size_t)NN * 4);
    float* h1   = (float*)w; w += align((size_t)NN * FHID * 4);
    float* agg1 = (float*)w; w += align((size_t)NN * FHID * 4);
    float* h2   = (float*)w; w += align((size_t)NN * FIN * 4);

    hipMemsetAsync(deg, 0, (size_t)NN * 4, stream);
    hipMemsetAsync(agg1, 0, (size_t)NN * FHID * 4, stream);
    hipMemsetAsync(out, 0, (size_t)NN * FIN * 4, stream);

    const int* dst = ei + NE;
    k_deg<<<2048, 256, 0, stream>>>(dst, deg);
    k_dis<<<(NN + 255) / 256, 256, 0, stream>>>(deg, dis);
    k_gemm1<<<(NN + 7) / 8, 256, 0, stream>>>(x, W1, h1);
    k_agg1<<<(NE * 8 + 255) / 256, 256, 0, stream>>>(ei, dis, h1, agg1);
    k_epi1<<<(NN * FHID + 255) / 256, 256, 0, stream>>>(agg1, h1, dis, b1);
    k_gemm2<<<(NN + 3) / 4, 256, 0, stream>>>(agg1, W2, h2);
    k_agg2<<<(NE * 16 + 255) / 256, 256, 0, stream>>>(ei, dis, h2, out);
    k_epi2<<<(NN * FIN + 255) / 256, 256, 0, stream>>>(h2, dis, b2, out);
}

// Round 3
// 247.492 us; speedup vs baseline: 5.7294x; 5.7294x over previous
//
#include <hip/hip_runtime.h>

#define NN 100000
#define NE 1000000
#define FIN 64
#define FHID 32
#define NBLK ((NN + 255) / 256)   // 391

// ---------------- degree (counts of dst) ----------------
__global__ __launch_bounds__(256) void k_deg(const int* __restrict__ dst, int* __restrict__ deg) {
    int i = blockIdx.x * 256 + threadIdx.x;
    int stride = gridDim.x * 256;
    for (; i < NE; i += stride) atomicAdd(&deg[dst[i]], 1);
}

// ---------------- dis = rsqrt(deg+1) ----------------
__global__ __launch_bounds__(256) void k_dis(const int* __restrict__ deg, float* __restrict__ dis) {
    int i = blockIdx.x * 256 + threadIdx.x;
    if (i < NN) dis[i] = rsqrtf((float)deg[i] + 1.0f);
}

// ---------------- per-256-chunk sums of deg ----------------
__global__ __launch_bounds__(256) void k_bsum(const int* __restrict__ deg, int* __restrict__ bsum) {
    __shared__ int s[256];
    int i = blockIdx.x * 256 + threadIdx.x;
    s[threadIdx.x] = (i < NN) ? deg[i] : 0;
    __syncthreads();
    for (int d = 128; d > 0; d >>= 1) {
        if (threadIdx.x < d) s[threadIdx.x] += s[threadIdx.x + d];
        __syncthreads();
    }
    if (threadIdx.x == 0) bsum[blockIdx.x] = s[0];
}

// ---------------- exclusive scan of the 391 block sums (one block) ----------------
__global__ __launch_bounds__(512) void k_scanb(const int* __restrict__ bsum, int* __restrict__ bsumx,
                                               int* __restrict__ off) {
    __shared__ int s[512];
    int v = (threadIdx.x < NBLK) ? bsum[threadIdx.x] : 0;
    s[threadIdx.x] = v;
    __syncthreads();
    for (int d = 1; d < 512; d <<= 1) {
        int t = (threadIdx.x >= d) ? s[threadIdx.x - d] : 0;
        __syncthreads();
        s[threadIdx.x] += t;
        __syncthreads();
    }
    if (threadIdx.x < NBLK) bsumx[threadIdx.x] = s[threadIdx.x] - v;
    if (threadIdx.x == 0) off[NN] = NE;
}

// ---------------- per-element exclusive offsets ----------------
__global__ __launch_bounds__(256) void k_off(const int* __restrict__ deg, const int* __restrict__ bsumx,
                                             int* __restrict__ off) {
    __shared__ int s[256];
    int i = blockIdx.x * 256 + threadIdx.x;
    int v = (i < NN) ? deg[i] : 0;
    s[threadIdx.x] = v;
    __syncthreads();
    for (int d = 1; d < 256; d <<= 1) {
        int t = (threadIdx.x >= d) ? s[threadIdx.x - d] : 0;
        __syncthreads();
        s[threadIdx.x] += t;
        __syncthreads();
    }
    if (i < NN) off[i] = bsumx[blockIdx.x] + (s[threadIdx.x] - v);
}

// ---------------- CSR fill: csr[pos] = {src, norm} ----------------
__global__ __launch_bounds__(256) void k_fill(const int* __restrict__ ei, const int* __restrict__ off,
                                              int* __restrict__ cur, const float* __restrict__ dis,
                                              int2* __restrict__ csr) {
    int e = blockIdx.x * 256 + threadIdx.x;
    if (e >= NE) return;
    int s = ei[e];
    int d = ei[NE + e];
    int pos = off[d] + atomicAdd(&cur[d], 1);
    float nrm = dis[s] * dis[d];
    csr[pos] = make_int2(s, __float_as_int(nrm));
}

// ---------------- h1 = x @ W1   [NN,64]x[64,32] ----------------
__global__ __launch_bounds__(256) void k_gemm1(const float* __restrict__ x, const float* __restrict__ W1,
                                               float* __restrict__ h1) {
    __shared__ float Wl[FIN * FHID];
    for (int t = threadIdx.x; t < FIN * FHID; t += 256) Wl[t] = W1[t];
    __syncthreads();
    int row = blockIdx.x * 8 + (threadIdx.x >> 5);
    int col = threadIdx.x & 31;
    if (row >= NN) return;
    const float* xr = x + (size_t)row * FIN;
    float acc = 0.f;
#pragma unroll
    for (int k = 0; k < FIN; ++k) acc += xr[k] * Wl[k * FHID + col];
    h1[(size_t)row * FHID + col] = acc;
}

// ---------------- gather layer1 (fused agg + self-loop + bias + relu) ----------------
// 8 lanes per node, float4 each -> 32 cols
__global__ __launch_bounds__(256) void k_gather1(const int* __restrict__ off, const int2* __restrict__ csr,
                                                 const float* __restrict__ dis, const float* __restrict__ h1,
                                                 const float* __restrict__ b1, float* __restrict__ hout) {
    int t = blockIdx.x * 256 + threadIdx.x;
    int n = t >> 3;
    int l = t & 7;
    if (n >= NN) return;
    float dn = dis[n];
    int beg = off[n], end = off[n + 1];
    float4 acc = make_float4(0.f, 0.f, 0.f, 0.f);
    if (beg < end) {
        int2 pr = csr[beg];
        for (int p = beg; p < end; ++p) {
            int s = pr.x;
            float nr = __int_as_float(pr.y);
            if (p + 1 < end) pr = csr[p + 1];
            const float4 v = *reinterpret_cast<const float4*>(h1 + (size_t)s * FHID + l * 4);
            acc.x += v.x * nr; acc.y += v.y * nr; acc.z += v.z * nr; acc.w += v.w * nr;
        }
    }
    float d2 = dn * dn;
    const float4 hv = *reinterpret_cast<const float4*>(h1 + (size_t)n * FHID + l * 4);
    const float4 bb = *reinterpret_cast<const float4*>(b1 + l * 4);
    float4 r;
    r.x = acc.x + hv.x * d2 + bb.x;
    r.y = acc.y + hv.y * d2 + bb.y;
    r.z = acc.z + hv.z * d2 + bb.z;
    r.w = acc.w + hv.w * d2 + bb.w;
    r.x = r.x > 0.f ? r.x : 0.f;
    r.y = r.y > 0.f ? r.y : 0.f;
    r.z = r.z > 0.f ? r.z : 0.f;
    r.w = r.w > 0.f ? r.w : 0.f;
    *reinterpret_cast<float4*>(hout + (size_t)n * FHID + l * 4) = r;
}

// ---------------- h2 = h @ W2   [NN,32]x[32,64] ----------------
__global__ __launch_bounds__(256) void k_gemm2(const float* __restrict__ h, const float* __restrict__ W2,
                                               float* __restrict__ h2) {
    __shared__ float Wl[FHID * FIN];
    for (int t = threadIdx.x; t < FHID * FIN; t += 256) Wl[t] = W2[t];
    __syncthreads();
    int row = blockIdx.x * 4 + (threadIdx.x >> 6);
    int col = threadIdx.x & 63;
    if (row >= NN) return;
    const float* hr = h + (size_t)row * FHID;
    float acc = 0.f;
#pragma unroll
    for (int k = 0; k < FHID; ++k) acc += hr[k] * Wl[k * FIN + col];
    h2[(size_t)row * FIN + col] = acc;
}

// ---------------- gather layer2 (fused agg + self-loop + bias) -> out ----------------
// 16 lanes per node, float4 each -> 64 cols
__global__ __launch_bounds__(256) void k_gather2(const int* __restrict__ off, const int2* __restrict__ csr,
                                                 const float* __restrict__ dis, const float* __restrict__ h2,
                                                 const float* __restrict__ b2, float* __restrict__ out) {
    int t = blockIdx.x * 256 + threadIdx.x;
    int n = t >> 4;
    int l = t & 15;
    if (n >= NN) return;
    float dn = dis[n];
    int beg = off[n], end = off[n + 1];
    float4 acc = make_float4(0.f, 0.f, 0.f, 0.f);
    if (beg < end) {
        int2 pr = csr[beg];
        for (int p = beg; p < end; ++p) {
            int s = pr.x;
            float nr = __int_as_float(pr.y);
            if (p + 1 < end) pr = csr[p + 1];
            const float4 v = *reinterpret_cast<const float4*>(h2 + (size_t)s * FIN + l * 4);
            acc.x += v.x * nr; acc.y += v.y * nr; acc.z += v.z * nr; acc.w += v.w * nr;
        }
    }
    float d2 = dn * dn;
    const float4 hv = *reinterpret_cast<const float4*>(h2 + (size_t)n * FIN + l * 4);
    const float4 bb = *reinterpret_cast<const float4*>(b2 + l * 4);
    float4 r;
    r.x = acc.x + hv.x * d2 + bb.x;
    r.y = acc.y + hv.y * d2 + bb.y;
    r.z = acc.z + hv.z * d2 + bb.z;
    r.w = acc.w + hv.w * d2 + bb.w;
    *reinterpret_cast<float4*>(out + (size_t)n * FIN + l * 4) = r;
}

extern "C" void kernel_launch(void* const* d_in, const int* in_sizes, int n_in,
                              void* d_out, int out_size, void* d_ws, size_t ws_size,
                              hipStream_t stream) {
    const float* x  = (const float*)d_in[0];
    const int*   ei = (const int*)d_in[1];
    const float* W1 = (const float*)d_in[2];
    const float* b1 = (const float*)d_in[3];
    const float* W2 = (const float*)d_in[4];
    const float* b2 = (const float*)d_in[5];
    float* out = (float*)d_out;

    char* w = (char*)d_ws;
    auto align = [](size_t v) { return (v + 255) & ~(size_t)255; };
    int*   deg   = (int*)w;    w += align((size_t)NN * 4);
    int*   cur   = (int*)w;    w += align((size_t)NN * 4);
    float* dis   = (float*)w;  w += align((size_t)NN * 4);
    int*   off   = (int*)w;    w += align((size_t)(NN + 1) * 4);
    int*   bsum  = (int*)w;    w += align((size_t)NBLK * 4);
    int*   bsumx = (int*)w;    w += align((size_t)NBLK * 4);
    int2*  csr   = (int2*)w;   w += align((size_t)NE * 8);
    float* hbuf  = (float*)w;  w += align((size_t)NN * FHID * 4);
    float* h1    = (float*)w;  // h2 aliases h1 (h1 dead once gemm2 runs)
    float* h2    = (float*)w;  w += align((size_t)NN * FIN * 4);

    // zero BOTH deg and cur over their true aligned extent
    // (R1 bug: NN*4 isn't 256-aligned, so a single NN*8 memset left the
    //  tail of cur poisoned -> wild CSR positions -> memory fault)
    size_t zext = (size_t)((char*)cur - (char*)deg) + (size_t)NN * 4;
    hipMemsetAsync(deg, 0, zext, stream);

    const int* dst = ei + NE;
    k_deg  <<<2048, 256, 0, stream>>>(dst, deg);
    k_dis  <<<(NN + 255) / 256, 256, 0, stream>>>(deg, dis);
    k_bsum <<<NBLK, 256, 0, stream>>>(deg, bsum);
    k_scanb<<<1, 512, 0, stream>>>(bsum, bsumx, off);
    k_off  <<<NBLK, 256, 0, stream>>>(deg, bsumx, off);
    k_fill <<<(NE + 255) / 256, 256, 0, stream>>>(ei, off, cur, dis, csr);
    k_gemm1<<<(NN + 7) / 8, 256, 0, stream>>>(x, W1, h1);
    k_gather1<<<(NN * 8) / 256, 256, 0, stream>>>(off, csr, dis, h1, b1, hbuf);
    k_gemm2<<<(NN + 3) / 4, 256, 0, stream>>>(hbuf, W2, h2);
    k_gather2<<<(NN * 16) / 256, 256, 0, stream>>>(off, csr, dis, h2, b2, out);
}

// Round 4
// 212.996 us; speedup vs baseline: 6.6573x; 1.1620x over previous
//
#include <hip/hip_runtime.h>

#define NN 100000
#define NE 1000000
#define FIN 64
#define FHID 32

// ---------------- degree + per-edge rank: rank[e] = arrival order at dst ----------------
__global__ __launch_bounds__(256) void k_deg(const int* __restrict__ dst, int* __restrict__ deg,
                                             int* __restrict__ rank) {
    int e = blockIdx.x * 256 + threadIdx.x;
    if (e >= NE) return;
    rank[e] = atomicAdd(&deg[dst[e]], 1);
}

// ---------------- dis = rsqrt(deg+1); off[n] = bump-allocate deg[n] slots ----------------
// CSR ranges need not be in node order -> no scan needed.
__global__ __launch_bounds__(256) void k_alloc(const int* __restrict__ deg, float* __restrict__ dis,
                                               int* __restrict__ off, int* __restrict__ ctr) {
    int n = blockIdx.x * 256 + threadIdx.x;
    if (n >= NN) return;
    int d = deg[n];
    dis[n] = rsqrtf((float)d + 1.0f);
    off[n] = atomicAdd(ctr, d);
}

// ---------------- CSR fill (no atomics): csr[off[dst]+rank] = src ----------------
__global__ __launch_bounds__(256) void k_fill(const int* __restrict__ ei, const int* __restrict__ off,
                                              const int* __restrict__ rank, int* __restrict__ csr) {
    int e = blockIdx.x * 256 + threadIdx.x;
    if (e >= NE) return;
    int s = ei[e];
    int d = ei[NE + e];
    csr[off[d] + rank[e]] = s;
}

// ---------------- h1 = x @ W1   [NN,64]x[64,32] ----------------
__global__ __launch_bounds__(256) void k_gemm1(const float* __restrict__ x, const float* __restrict__ W1,
                                               float* __restrict__ h1) {
    __shared__ float Wl[FIN * FHID];
    for (int t = threadIdx.x; t < FIN * FHID; t += 256) Wl[t] = W1[t];
    __syncthreads();
    int row = blockIdx.x * 8 + (threadIdx.x >> 5);
    int col = threadIdx.x & 31;
    if (row >= NN) return;
    const float* xr = x + (size_t)row * FIN;
    float acc = 0.f;
#pragma unroll
    for (int k = 0; k < FIN; ++k) acc += xr[k] * Wl[k * FHID + col];
    h1[(size_t)row * FHID + col] = acc;
}

// ---------------- gather over 32-col feature matrix ----------------
// MODE 1: layer1 -> out = relu(agg + dis^2*h_n + b);  MODE 0: layer2 pre-GEMM -> out = agg + dis^2*h_n
// 8 lanes per node, float4 each. norm recomputed from dis (cache-resident).
template <int MODE>
__global__ __launch_bounds__(256) void k_gather(const int* __restrict__ off, const int* __restrict__ deg,
                                                const int* __restrict__ csr, const float* __restrict__ dis,
                                                const float* __restrict__ h, const float* __restrict__ bias,
                                                float* __restrict__ out) {
    int t = blockIdx.x * 256 + threadIdx.x;
    int n = t >> 3;
    int l = t & 7;
    if (n >= NN) return;
    float dn = dis[n];
    int beg = off[n];
    int end = beg + deg[n];
    float4 acc = make_float4(0.f, 0.f, 0.f, 0.f);
    if (beg < end) {
        int s = csr[beg];
        for (int p = beg; p < end; ++p) {
            int scur = s;
            if (p + 1 < end) s = csr[p + 1];
            float nr = dis[scur] * dn;
            const float4 v = *reinterpret_cast<const float4*>(h + (size_t)scur * FHID + l * 4);
            acc.x += v.x * nr; acc.y += v.y * nr; acc.z += v.z * nr; acc.w += v.w * nr;
        }
    }
    float d2 = dn * dn;
    const float4 hv = *reinterpret_cast<const float4*>(h + (size_t)n * FHID + l * 4);
    float4 r;
    r.x = acc.x + hv.x * d2;
    r.y = acc.y + hv.y * d2;
    r.z = acc.z + hv.z * d2;
    r.w = acc.w + hv.w * d2;
    if (MODE == 1) {
        const float4 bb = *reinterpret_cast<const float4*>(bias + l * 4);
        r.x += bb.x; r.y += bb.y; r.z += bb.z; r.w += bb.w;
        r.x = r.x > 0.f ? r.x : 0.f;
        r.y = r.y > 0.f ? r.y : 0.f;
        r.z = r.z > 0.f ? r.z : 0.f;
        r.w = r.w > 0.f ? r.w : 0.f;
    }
    *reinterpret_cast<float4*>(out + (size_t)n * FHID + l * 4) = r;
}

// ---------------- out = agg2 @ W2 + b2   [NN,32]x[32,64] ----------------
__global__ __launch_bounds__(256) void k_gemm2(const float* __restrict__ a, const float* __restrict__ W2,
                                               const float* __restrict__ b2, float* __restrict__ out) {
    __shared__ float Wl[FHID * FIN];
    for (int t = threadIdx.x; t < FHID * FIN; t += 256) Wl[t] = W2[t];
    __syncthreads();
    int row = blockIdx.x * 4 + (threadIdx.x >> 6);
    int col = threadIdx.x & 63;
    if (row >= NN) return;
    const float* ar = a + (size_t)row * FHID;
    float acc = b2[col];
#pragma unroll
    for (int k = 0; k < FHID; ++k) acc += ar[k] * Wl[k * FIN + col];
    out[(size_t)row * FIN + col] = acc;
}

extern "C" void kernel_launch(void* const* d_in, const int* in_sizes, int n_in,
                              void* d_out, int out_size, void* d_ws, size_t ws_size,
                              hipStream_t stream) {
    const float* x  = (const float*)d_in[0];
    const int*   ei = (const int*)d_in[1];
    const float* W1 = (const float*)d_in[2];
    const float* b1 = (const float*)d_in[3];
    const float* W2 = (const float*)d_in[4];
    const float* b2 = (const float*)d_in[5];
    float* out = (float*)d_out;

    char* w = (char*)d_ws;
    auto align = [](size_t v) { return (v + 255) & ~(size_t)255; };
    int*   deg  = (int*)w;   w += align((size_t)NN * 4 + 4);  // ctr lives at deg[NN]
    int*   ctr  = deg + NN;
    int*   rank = (int*)w;   w += align((size_t)NE * 4);
    float* dis  = (float*)w; w += align((size_t)NN * 4);
    int*   off  = (int*)w;   w += align((size_t)NN * 4);
    int*   csr  = (int*)w;   w += align((size_t)NE * 4);
    float* h1   = (float*)w; w += align((size_t)NN * FHID * 4);
    float* hbuf = (float*)w; w += align((size_t)NN * FHID * 4);
    float* agg2 = (float*)w; w += align((size_t)NN * FHID * 4);

    // zero deg AND ctr in one memset (covers deg[0..NN] inclusive of ctr)
    hipMemsetAsync(deg, 0, (size_t)NN * 4 + 4, stream);

    const int* dst = ei + NE;
    k_deg  <<<(NE + 255) / 256, 256, 0, stream>>>(dst, deg, rank);
    k_alloc<<<(NN + 255) / 256, 256, 0, stream>>>(deg, dis, off, ctr);
    k_fill <<<(NE + 255) / 256, 256, 0, stream>>>(ei, off, rank, csr);
    k_gemm1<<<(NN + 7) / 8, 256, 0, stream>>>(x, W1, h1);
    k_gather<1><<<(NN * 8) / 256, 256, 0, stream>>>(off, deg, csr, dis, h1, b1, hbuf);
    k_gather<0><<<(NN * 8) / 256, 256, 0, stream>>>(off, deg, csr, dis, hbuf, nullptr, agg2);
    k_gemm2<<<(NN + 3) / 4, 256, 0, stream>>>(agg2, W2, b2, out);
}

// Round 5
// 159.887 us; speedup vs baseline: 8.8686x; 1.3322x over previous
//
#include <hip/hip_runtime.h>

#define NN 100000
#define NE 1000000
#define FIN 64
#define FHID 32

// ---------------- degree + per-edge rank: rank[e] = arrival order at dst ----------------
__global__ __launch_bounds__(256) void k_deg(const int* __restrict__ dst, int* __restrict__ deg,
                                             int* __restrict__ rank) {
    int e = blockIdx.x * 256 + threadIdx.x;
    if (e >= NE) return;
    rank[e] = atomicAdd(&deg[dst[e]], 1);
}

// ---------------- dis = rsqrt(deg+1); off[n] = bump-allocate deg[n] slots ----------------
__global__ __launch_bounds__(256) void k_alloc(const int* __restrict__ deg, float* __restrict__ dis,
                                               int* __restrict__ off, int* __restrict__ ctr) {
    int n = blockIdx.x * 256 + threadIdx.x;
    if (n >= NN) return;
    int d = deg[n];
    dis[n] = rsqrtf((float)d + 1.0f);
    off[n] = atomicAdd(ctr, d);
}

// ---------------- CSR fill (no atomics): csr[off[dst]+rank] = src ----------------
__global__ __launch_bounds__(256) void k_fill(const int* __restrict__ ei, const int* __restrict__ off,
                                              const int* __restrict__ rank, int* __restrict__ csr) {
    int e = blockIdx.x * 256 + threadIdx.x;
    if (e >= NE) return;
    int s = ei[e];
    int d = ei[NE + e];
    csr[off[d] + rank[e]] = s;
}

// ---------------- h1 = x @ W1   [NN,64]x[64,32] — 8 lanes/row, float4 acc ----------------
__global__ __launch_bounds__(256) void k_gemm1(const float* __restrict__ x, const float* __restrict__ W1,
                                               float* __restrict__ h1) {
    __shared__ float Wl[FIN * FHID];  // 8 KB
    for (int t = threadIdx.x; t < FIN * FHID / 4; t += 256)
        reinterpret_cast<float4*>(Wl)[t] = reinterpret_cast<const float4*>(W1)[t];
    __syncthreads();
    int row = blockIdx.x * 32 + (threadIdx.x >> 3);
    int l = threadIdx.x & 7;  // 8 lanes per row, 4 cols each
    if (row >= NN) return;
    const float4* xr = reinterpret_cast<const float4*>(x + (size_t)row * FIN);
    float4 acc = make_float4(0.f, 0.f, 0.f, 0.f);
#pragma unroll
    for (int k4 = 0; k4 < FIN / 4; ++k4) {
        float4 a4 = xr[k4];
#pragma unroll
        for (int j = 0; j < 4; ++j) {
            float a = j == 0 ? a4.x : j == 1 ? a4.y : j == 2 ? a4.z : a4.w;
            const float4 wv = *reinterpret_cast<const float4*>(Wl + (k4 * 4 + j) * FHID + l * 4);
            acc.x += a * wv.x; acc.y += a * wv.y; acc.z += a * wv.z; acc.w += a * wv.w;
        }
    }
    *reinterpret_cast<float4*>(h1 + (size_t)row * FHID + l * 4) = acc;
}

// ---------------- gather layer1: hbuf = relu(agg + dis^2*h1 + b1) ----------------
__global__ __launch_bounds__(256) void k_gather1(const int* __restrict__ off, const int* __restrict__ deg,
                                                 const int* __restrict__ csr, const float* __restrict__ dis,
                                                 const float* __restrict__ h, const float* __restrict__ bias,
                                                 float* __restrict__ out) {
    int t = blockIdx.x * 256 + threadIdx.x;
    int n = t >> 3;
    int l = t & 7;
    if (n >= NN) return;
    float dn = dis[n];
    int beg = off[n];
    int end = beg + deg[n];
    float4 acc = make_float4(0.f, 0.f, 0.f, 0.f);
    if (beg < end) {
        int s = csr[beg];
        for (int p = beg; p < end; ++p) {
            int scur = s;
            if (p + 1 < end) s = csr[p + 1];
            float nr = dis[scur] * dn;
            const float4 v = *reinterpret_cast<const float4*>(h + (size_t)scur * FHID + l * 4);
            acc.x += v.x * nr; acc.y += v.y * nr; acc.z += v.z * nr; acc.w += v.w * nr;
        }
    }
    float d2 = dn * dn;
    const float4 hv = *reinterpret_cast<const float4*>(h + (size_t)n * FHID + l * 4);
    const float4 bb = *reinterpret_cast<const float4*>(bias + l * 4);
    float4 r;
    r.x = acc.x + hv.x * d2 + bb.x;
    r.y = acc.y + hv.y * d2 + bb.y;
    r.z = acc.z + hv.z * d2 + bb.z;
    r.w = acc.w + hv.w * d2 + bb.w;
    r.x = r.x > 0.f ? r.x : 0.f;
    r.y = r.y > 0.f ? r.y : 0.f;
    r.z = r.z > 0.f ? r.z : 0.f;
    r.w = r.w > 0.f ? r.w : 0.f;
    *reinterpret_cast<float4*>(out + (size_t)n * FHID + l * 4) = r;
}

// ---------------- fused: agg2 (gather of hbuf) -> LDS -> @W2 + b2 -> out ----------------
// 32 nodes/block. Phase A: 8 lanes/node gather agg row (32 f32) into LDS.
// Phase B: 8 lanes/row x 8 cols each: out[row] = aggL[row] @ W2 + b2.
__global__ __launch_bounds__(256) void k_gather_mm(const int* __restrict__ off, const int* __restrict__ deg,
                                                   const int* __restrict__ csr, const float* __restrict__ dis,
                                                   const float* __restrict__ h, const float* __restrict__ W2,
                                                   const float* __restrict__ b2, float* __restrict__ out) {
    __shared__ float WL[FHID * FIN];   // 8 KB
    __shared__ float aggL[32 * FHID];  // 4 KB
    for (int t = threadIdx.x; t < FHID * FIN / 4; t += 256)
        reinterpret_cast<float4*>(WL)[t] = reinterpret_cast<const float4*>(W2)[t];

    int i = threadIdx.x >> 3;  // local node 0..31
    int l = threadIdx.x & 7;   // lane-in-node, 4 cols each
    int n = blockIdx.x * 32 + i;

    // ---- phase A: gather ----
    {
        float dn = dis[n];
        int beg = off[n];
        int end = beg + deg[n];
        float4 acc = make_float4(0.f, 0.f, 0.f, 0.f);
        if (beg < end) {
            int s = csr[beg];
            for (int p = beg; p < end; ++p) {
                int scur = s;
                if (p + 1 < end) s = csr[p + 1];
                float nr = dis[scur] * dn;
                const float4 v = *reinterpret_cast<const float4*>(h + (size_t)scur * FHID + l * 4);
                acc.x += v.x * nr; acc.y += v.y * nr; acc.z += v.z * nr; acc.w += v.w * nr;
            }
        }
        float d2 = dn * dn;
        const float4 hv = *reinterpret_cast<const float4*>(h + (size_t)n * FHID + l * 4);
        acc.x += hv.x * d2; acc.y += hv.y * d2; acc.z += hv.z * d2; acc.w += hv.w * d2;
        *reinterpret_cast<float4*>(aggL + i * FHID + l * 4) = acc;
    }
    __syncthreads();

    // ---- phase B: [32,32] @ [32,64] ----
    {
        int c0 = l * 8;  // 8 output cols per thread
        float4 acc0 = *reinterpret_cast<const float4*>(b2 + c0);
        float4 acc1 = *reinterpret_cast<const float4*>(b2 + c0 + 4);
        const float4* ar = reinterpret_cast<const float4*>(aggL + i * FHID);
#pragma unroll
        for (int k4 = 0; k4 < FHID / 4; ++k4) {
            float4 a4 = ar[k4];
#pragma unroll
            for (int j = 0; j < 4; ++j) {
                float a = j == 0 ? a4.x : j == 1 ? a4.y : j == 2 ? a4.z : a4.w;
                const float* wr = WL + (k4 * 4 + j) * FIN + c0;
                const float4 w0 = *reinterpret_cast<const float4*>(wr);
                const float4 w1 = *reinterpret_cast<const float4*>(wr + 4);
                acc0.x += a * w0.x; acc0.y += a * w0.y; acc0.z += a * w0.z; acc0.w += a * w0.w;
                acc1.x += a * w1.x; acc1.y += a * w1.y; acc1.z += a * w1.z; acc1.w += a * w1.w;
            }
        }
        float* o = out + (size_t)n * FIN + c0;
        *reinterpret_cast<float4*>(o) = acc0;
        *reinterpret_cast<float4*>(o + 4) = acc1;
    }
}

extern "C" void kernel_launch(void* const* d_in, const int* in_sizes, int n_in,
                              void* d_out, int out_size, void* d_ws, size_t ws_size,
                              hipStream_t stream) {
    const float* x  = (const float*)d_in[0];
    const int*   ei = (const int*)d_in[1];
    const float* W1 = (const float*)d_in[2];
    const float* b1 = (const float*)d_in[3];
    const float* W2 = (const float*)d_in[4];
    const float* b2 = (const float*)d_in[5];
    float* out = (float*)d_out;

    char* w = (char*)d_ws;
    auto align = [](size_t v) { return (v + 255) & ~(size_t)255; };
    int*   deg  = (int*)w;   w += align((size_t)NN * 4 + 4);  // ctr at deg[NN]
    int*   ctr  = deg + NN;
    int*   rank = (int*)w;   w += align((size_t)NE * 4);
    float* dis  = (float*)w; w += align((size_t)NN * 4);
    int*   off  = (int*)w;   w += align((size_t)NN * 4);
    int*   csr  = (int*)w;   w += align((size_t)NE * 4);
    float* h1   = (float*)w; w += align((size_t)NN * FHID * 4);
    float* hbuf = (float*)w; w += align((size_t)NN * FHID * 4);

    hipMemsetAsync(deg, 0, (size_t)NN * 4 + 4, stream);

    const int* dst = ei + NE;
    k_deg  <<<(NE + 255) / 256, 256, 0, stream>>>(dst, deg, rank);
    k_alloc<<<(NN + 255) / 256, 256, 0, stream>>>(deg, dis, off, ctr);
    k_fill <<<(NE + 255) / 256, 256, 0, stream>>>(ei, off, rank, csr);
    k_gemm1<<<(NN + 31) / 32, 256, 0, stream>>>(x, W1, h1);
    k_gather1<<<(NN * 8) / 256, 256, 0, stream>>>(off, deg, csr, dis, h1, b1, hbuf);
    k_gather_mm<<<NN / 32, 256, 0, stream>>>(off, deg, csr, dis, hbuf, W2, b2, out);
}